// Round 1
// baseline (207.590 us; speedup 1.0000x reference)
//
#include <hip/hip_runtime.h>
#include <hip/hip_bf16.h>

#define B_ 8
#define S_ 2048
#define F_ 1024
#define DK_ 128
#define M_ (B_*S_)          // 16384
#define LOG2E 1.4426950408889634f

typedef unsigned short u16;
typedef short short8 __attribute__((ext_vector_type(8)));
typedef float f32x4 __attribute__((ext_vector_type(4)));

__device__ __forceinline__ u16 f2bf(float f) {
    unsigned int u = __float_as_uint(f);
    u += 0x7FFFu + ((u >> 16) & 1u);    // round-to-nearest-even
    return (u16)(u >> 16);
}
__device__ __forceinline__ unsigned int pack2(float a, float b) {
    return (unsigned int)f2bf(a) | ((unsigned int)f2bf(b) << 16);
}

// ---------------------------------------------------------------------------
// Kernel 1: W [1024][128] fp32 -> WT [3][128][1024] bf16 (transposed),
// 1/sqrt(DK) folded into w_q.
// ---------------------------------------------------------------------------
__global__ __launch_bounds__(256) void prep_wt(const float* __restrict__ wq,
                                               const float* __restrict__ wk,
                                               const float* __restrict__ wv,
                                               u16* __restrict__ WT) {
    int id = blockIdx.x * 256 + threadIdx.x;
    if (id >= 3 * DK_ * F_) return;
    int m   = id / (DK_ * F_);
    int rem = id - m * (DK_ * F_);
    int c   = rem / F_;
    int k   = rem - c * F_;
    const float* w = (m == 0) ? wq : (m == 1) ? wk : wv;
    float v = w[k * DK_ + c];
    if (m == 0) v *= 0.08838834764831845f;   // 1/sqrt(128)
    WT[id] = f2bf(v);
}

// ---------------------------------------------------------------------------
// Kernel 2: projection GEMM.  X [16384][1024] fp32  x  W -> bf16 outputs.
// mode 0: qp [16384][128], mode 1: kp [16384][128], mode 2: vpT [128][16384]
// Block 256 thr (4 waves), tile 128 rows x 128 cols, BK=32.
// ---------------------------------------------------------------------------
__global__ __launch_bounds__(256) void proj(const float* __restrict__ xq,
                                            const float* __restrict__ xk,
                                            const float* __restrict__ xv,
                                            const u16* __restrict__ WT,
                                            u16* __restrict__ qp,
                                            u16* __restrict__ kp,
                                            u16* __restrict__ vpT) {
    const int mode = blockIdx.y;
    const float* X = (mode == 0) ? xq : (mode == 1) ? xk : xv;
    const u16*   W = WT + mode * (DK_ * F_);

    __shared__ u16 a_lds[128][40];   // +8 pad kills bank conflicts, keeps 16B align
    __shared__ u16 w_lds[128][40];

    const int t    = threadIdx.x;
    const int lane = t & 63;
    const int wv_  = t >> 6;
    const int l15  = lane & 15, l4 = lane >> 4;
    const int row0 = blockIdx.x * 128;

    f32x4 acc[2][8];
#pragma unroll
    for (int i = 0; i < 2; ++i)
#pragma unroll
        for (int j = 0; j < 8; ++j) acc[i][j] = f32x4{0.f, 0.f, 0.f, 0.f};

    for (int k0 = 0; k0 < F_; k0 += 32) {
        // stage A tile (fp32 -> bf16)
        {
            int r = t >> 1, kk = (t & 1) * 16;
            const float4* src = (const float4*)(X + (size_t)(row0 + r) * F_ + k0 + kk);
            float4 f0 = src[0], f1 = src[1], f2 = src[2], f3 = src[3];
            int4 o0, o1;
            o0.x = pack2(f0.x, f0.y); o0.y = pack2(f0.z, f0.w);
            o0.z = pack2(f1.x, f1.y); o0.w = pack2(f1.z, f1.w);
            o1.x = pack2(f2.x, f2.y); o1.y = pack2(f2.z, f2.w);
            o1.z = pack2(f3.x, f3.y); o1.w = pack2(f3.z, f3.w);
            *(int4*)&a_lds[r][kk]     = o0;
            *(int4*)&a_lds[r][kk + 8] = o1;
        }
        // stage W^T tile (already bf16)
        {
            int c = t >> 1, kk = (t & 1) * 16;
            const int4* src = (const int4*)(W + (size_t)c * F_ + k0 + kk);
            *(int4*)&w_lds[c][kk]     = src[0];
            *(int4*)&w_lds[c][kk + 8] = src[1];
        }
        __syncthreads();

        short8 af[2], bf[8];
#pragma unroll
        for (int rt = 0; rt < 2; ++rt)
            af[rt] = *(const short8*)&a_lds[wv_ * 32 + rt * 16 + l15][l4 * 8];
#pragma unroll
        for (int ct = 0; ct < 8; ++ct)
            bf[ct] = *(const short8*)&w_lds[ct * 16 + l15][l4 * 8];

        if (mode < 2) {
#pragma unroll
            for (int rt = 0; rt < 2; ++rt)
#pragma unroll
                for (int ct = 0; ct < 8; ++ct)
                    acc[rt][ct] = __builtin_amdgcn_mfma_f32_16x16x32_bf16(
                        af[rt], bf[ct], acc[rt][ct], 0, 0, 0);
        } else {
#pragma unroll
            for (int rt = 0; rt < 2; ++rt)
#pragma unroll
                for (int ct = 0; ct < 8; ++ct)
                    acc[rt][ct] = __builtin_amdgcn_mfma_f32_16x16x32_bf16(
                        bf[ct], af[rt], acc[rt][ct], 0, 0, 0);
        }
        __syncthreads();
    }

    if (mode < 2) {
        u16* OUT = (mode == 0) ? qp : kp;
#pragma unroll
        for (int rt = 0; rt < 2; ++rt)
#pragma unroll
            for (int ct = 0; ct < 8; ++ct)
#pragma unroll
                for (int r = 0; r < 4; ++r) {
                    int row = row0 + wv_ * 32 + rt * 16 + l4 * 4 + r;
                    int col = ct * 16 + l15;
                    OUT[(size_t)row * DK_ + col] = f2bf(acc[rt][ct][r]);
                }
    } else {
        // swapped operands: D[row=n][col=m] -> store transposed vpT[n][m]
#pragma unroll
        for (int rt = 0; rt < 2; ++rt)
#pragma unroll
            for (int ct = 0; ct < 8; ++ct)
#pragma unroll
                for (int r = 0; r < 4; ++r) {
                    int n = ct * 16 + l4 * 4 + r;
                    int m = row0 + wv_ * 32 + rt * 16 + l15;
                    vpT[(size_t)n * M_ + m] = f2bf(acc[rt][ct][r]);
                }
    }
}

// ---------------------------------------------------------------------------
// Kernel 3: flash attention.  qp/kp [16384][128] bf16, vpT [128][16384] bf16.
// Block = 128 thr (2 waves), Q-tile 64 (32 rows/wave), KV-tile 64.
// Grid 256: blockIdx.x & 7 = batch (XCD-pins each batch's KV into one L2).
// ---------------------------------------------------------------------------
__global__ __launch_bounds__(128) void attn(const u16* __restrict__ qp,
                                            const u16* __restrict__ kp,
                                            const u16* __restrict__ vpT,
                                            float* __restrict__ out) {
    __shared__ __align__(16) unsigned char k_lds[64 * 256];   // [kv64][d128] bf16, swizzled
    __shared__ __align__(16) unsigned char v_lds[128 * 128];  // [d128][kv64] bf16, swizzled
    __shared__ __align__(16) unsigned char p_lds[64 * 128];   // [q64][kv64]  bf16, swizzled

    const int t    = threadIdx.x;
    const int lane = t & 63;
    const int wv_  = t >> 6;
    const int l15  = lane & 15, l4 = lane >> 4;

    const int b  = blockIdx.x & 7;
    const int q0 = (blockIdx.x >> 3) * 64;
    const int qbase = b * S_ + q0;

    // Q fragments in registers (scale already folded into w_q)
    short8 qf[2][4];
#pragma unroll
    for (int rt = 0; rt < 2; ++rt)
#pragma unroll
        for (int kc = 0; kc < 4; ++kc)
            qf[rt][kc] = *(const short8*)(qp + (size_t)(qbase + wv_ * 32 + rt * 16 + l15) * DK_
                                             + kc * 32 + l4 * 8);

    f32x4 o[2][8];
#pragma unroll
    for (int i = 0; i < 2; ++i)
#pragma unroll
        for (int j = 0; j < 8; ++j) o[i][j] = f32x4{0.f, 0.f, 0.f, 0.f};
    float mrun[2][4], lrun[2][4];
#pragma unroll
    for (int i = 0; i < 2; ++i)
#pragma unroll
        for (int r = 0; r < 4; ++r) { mrun[i][r] = -3.0e38f; lrun[i][r] = 0.f; }

    for (int kt = 0; kt < S_ / 64; ++kt) {
        const int kv0 = kt * 64;
        // ---- stage K tile [64][128]
        {
            int r = t >> 1, h = t & 1;
            const int4* src = (const int4*)(kp + (size_t)(b * S_ + kv0 + r) * DK_ + h * 64);
            int base = r * 256 + h * 128, sw = (r & 7) << 4;
#pragma unroll
            for (int j = 0; j < 8; ++j)
                *(int4*)(k_lds + ((base + j * 16) ^ sw)) = src[j];
        }
        // ---- stage V^T tile [128][64]
        {
            const int4* src = (const int4*)(vpT + (size_t)t * M_ + b * S_ + kv0);
            int base = t * 128, sw = (t & 7) << 4;
#pragma unroll
            for (int j = 0; j < 8; ++j)
                *(int4*)(v_lds + ((base + j * 16) ^ sw)) = src[j];
        }
        __syncthreads();

        // ---- QK^T: s[q 32][kv 64] per wave
        f32x4 s[2][4];
#pragma unroll
        for (int i = 0; i < 2; ++i)
#pragma unroll
            for (int j = 0; j < 4; ++j) s[i][j] = f32x4{0.f, 0.f, 0.f, 0.f};
#pragma unroll
        for (int ct = 0; ct < 4; ++ct) {
            int row = ct * 16 + l15, sw = (row & 7) << 4;
#pragma unroll
            for (int kc = 0; kc < 4; ++kc) {
                short8 kf = *(const short8*)(k_lds + ((row * 256 + kc * 64 + l4 * 16) ^ sw));
#pragma unroll
                for (int rt = 0; rt < 2; ++rt)
                    s[rt][ct] = __builtin_amdgcn_mfma_f32_16x16x32_bf16(
                        qf[rt][kc], kf, s[rt][ct], 0, 0, 0);
            }
        }

        // ---- online softmax (+ P -> LDS as bf16)
#pragma unroll
        for (int rt = 0; rt < 2; ++rt) {
            float fs[4], sum[4];
#pragma unroll
            for (int r = 0; r < 4; ++r) {
                float v0 = fmaxf(fmaxf(s[rt][0][r], s[rt][1][r]),
                                 fmaxf(s[rt][2][r], s[rt][3][r]));
#pragma unroll
                for (int msk = 1; msk < 16; msk <<= 1)
                    v0 = fmaxf(v0, __shfl_xor(v0, msk, 64));
                float mn = fmaxf(mrun[rt][r], v0);
                fs[r] = exp2f((mrun[rt][r] - mn) * LOG2E);
                mrun[rt][r] = mn;
                sum[r] = 0.f;
            }
#pragma unroll
            for (int ct = 0; ct < 4; ++ct)
#pragma unroll
                for (int r = 0; r < 4; ++r) {
                    float p = exp2f((s[rt][ct][r] - mrun[rt][r]) * LOG2E);
                    sum[r] += p;
                    int prow = wv_ * 32 + rt * 16 + l4 * 4 + r;
                    int pb = (prow * 128 + (ct * 16 + l15) * 2) ^ ((prow & 7) << 4);
                    *(u16*)(p_lds + pb) = f2bf(p);
                }
#pragma unroll
            for (int r = 0; r < 4; ++r) {
#pragma unroll
                for (int msk = 1; msk < 16; msk <<= 1)
                    sum[r] += __shfl_xor(sum[r], msk, 64);
                lrun[rt][r] = lrun[rt][r] * fs[r] + sum[r];
            }
#pragma unroll
            for (int ct = 0; ct < 8; ++ct)
#pragma unroll
                for (int r = 0; r < 4; ++r) o[rt][ct][r] *= fs[r];
        }

        // ---- PV: o[q 32][d 128] += P[q][kv] * V[kv][d]
#pragma unroll
        for (int kc = 0; kc < 2; ++kc) {
            short8 pf[2];
#pragma unroll
            for (int rt = 0; rt < 2; ++rt) {
                int prow = wv_ * 32 + rt * 16 + l15;
                pf[rt] = *(const short8*)(p_lds + ((prow * 128 + kc * 64 + l4 * 16)
                                                   ^ ((prow & 7) << 4)));
            }
#pragma unroll
            for (int ct = 0; ct < 8; ++ct) {
                int vrow = ct * 16 + l15;
                short8 vf = *(const short8*)(v_lds + ((vrow * 128 + kc * 64 + l4 * 16)
                                                      ^ ((vrow & 7) << 4)));
#pragma unroll
                for (int rt = 0; rt < 2; ++rt)
                    o[rt][ct] = __builtin_amdgcn_mfma_f32_16x16x32_bf16(
                        pf[rt], vf, o[rt][ct], 0, 0, 0);
            }
        }
        __syncthreads();
    }

    // ---- epilogue: divide by l, store fp32
#pragma unroll
    for (int rt = 0; rt < 2; ++rt) {
        float inv[4];
#pragma unroll
        for (int r = 0; r < 4; ++r) inv[r] = 1.0f / lrun[rt][r];
#pragma unroll
        for (int ct = 0; ct < 8; ++ct)
#pragma unroll
            for (int r = 0; r < 4; ++r) {
                int row = qbase + wv_ * 32 + rt * 16 + l4 * 4 + r;
                out[(size_t)row * DK_ + ct * 16 + l15] = o[rt][ct][r] * inv[r];
            }
    }
}

// ---------------------------------------------------------------------------
extern "C" void kernel_launch(void* const* d_in, const int* in_sizes, int n_in,
                              void* d_out, int out_size, void* d_ws, size_t ws_size,
                              hipStream_t stream) {
    const float* q  = (const float*)d_in[0];
    const float* k  = (const float*)d_in[1];
    const float* v  = (const float*)d_in[2];
    const float* wq = (const float*)d_in[3];
    const float* wk = (const float*)d_in[4];
    const float* wv = (const float*)d_in[5];
    float* out = (float*)d_out;

    char* ws = (char*)d_ws;
    u16* WT  = (u16*)ws;                                   // 3*128*1024*2 = 786432 B
    u16* qp  = (u16*)(ws + 786432);                        // 4 MB
    u16* kp  = (u16*)(ws + 786432 + 4194304);              // 4 MB
    u16* vpT = (u16*)(ws + 786432 + 2 * 4194304);          // 4 MB  (total ~12.75 MB)

    prep_wt<<<dim3(1536), dim3(256), 0, stream>>>(wq, wk, wv, WT);
    proj<<<dim3(128, 3), dim3(256), 0, stream>>>(q, k, v, WT, qp, kp, vpT);
    attn<<<dim3(256), dim3(128), 0, stream>>>(qp, kp, vpT, out);
}

// Round 2
// 131.577 us; speedup vs baseline: 1.5777x; 1.5777x over previous
//
#include <hip/hip_runtime.h>
#include <hip/hip_bf16.h>

#define B_ 8
#define S_ 2048
#define F_ 1024
#define DK_ 128
#define M_ (B_*S_)          // 16384
#define LOG2E 1.4426950408889634f

typedef unsigned short u16;
typedef short short8 __attribute__((ext_vector_type(8)));
typedef float f32x4 __attribute__((ext_vector_type(4)));

__device__ __forceinline__ u16 f2bf(float f) {
    unsigned int u = __float_as_uint(f);
    u += 0x7FFFu + ((u >> 16) & 1u);    // round-to-nearest-even
    return (u16)(u >> 16);
}
__device__ __forceinline__ unsigned int pack2(float a, float b) {
    return (unsigned int)f2bf(a) | ((unsigned int)f2bf(b) << 16);
}

// ---------------------------------------------------------------------------
// Kernel 1: W [1024][128] fp32 -> WT [3][128][1024] bf16 (transposed),
// 1/sqrt(DK) folded into w_q.
// ---------------------------------------------------------------------------
__global__ __launch_bounds__(256) void prep_wt(const float* __restrict__ wq,
                                               const float* __restrict__ wk,
                                               const float* __restrict__ wv,
                                               u16* __restrict__ WT) {
    int id = blockIdx.x * 256 + threadIdx.x;
    if (id >= 3 * DK_ * F_) return;
    int m   = id / (DK_ * F_);
    int rem = id - m * (DK_ * F_);
    int c   = rem / F_;
    int k   = rem - c * F_;
    const float* w = (m == 0) ? wq : (m == 1) ? wk : wv;
    float v = w[k * DK_ + c];
    if (m == 0) v *= 0.08838834764831845f;   // 1/sqrt(128)
    WT[id] = f2bf(v);
}

// ---------------------------------------------------------------------------
// Kernel 2: projection GEMM.  X [16384][1024] fp32  x  W -> bf16 outputs.
// mode 0: qp [16384][128], mode 1: kp [16384][128], mode 2: vpT [128][16384]
// Block 256 thr (4 waves), tile 64 rows x 128 cols (16 rows/wave), BK=32.
// 768 blocks total -> 3 blocks/CU, 12 waves/CU.
// ---------------------------------------------------------------------------
__global__ __launch_bounds__(256, 3) void proj(const float* __restrict__ xq,
                                               const float* __restrict__ xk,
                                               const float* __restrict__ xv,
                                               const u16* __restrict__ WT,
                                               u16* __restrict__ qp,
                                               u16* __restrict__ kp,
                                               u16* __restrict__ vpT) {
    const int mode = blockIdx.y;
    const float* X = (mode == 0) ? xq : (mode == 1) ? xk : xv;
    const u16*   W = WT + mode * (DK_ * F_);

    __shared__ u16 a_lds[64][40];    // row stride 80B (16B-aligned), bank-spread
    __shared__ u16 w_lds[128][40];

    const int t    = threadIdx.x;
    const int lane = t & 63;
    const int wv_  = t >> 6;
    const int l15  = lane & 15, l4 = lane >> 4;
    const int row0 = blockIdx.x * 64;

    f32x4 acc[8];
#pragma unroll
    for (int j = 0; j < 8; ++j) acc[j] = f32x4{0.f, 0.f, 0.f, 0.f};

    for (int k0 = 0; k0 < F_; k0 += 32) {
        // stage A tile 64x32 (fp32 -> bf16): thread -> row t>>2, k-chunk (t&3)*8
        {
            int r = t >> 2, kk = (t & 3) * 8;
            const float4* src = (const float4*)(X + (size_t)(row0 + r) * F_ + k0 + kk);
            float4 f0 = src[0], f1 = src[1];
            int4 o0;
            o0.x = pack2(f0.x, f0.y); o0.y = pack2(f0.z, f0.w);
            o0.z = pack2(f1.x, f1.y); o0.w = pack2(f1.z, f1.w);
            *(int4*)&a_lds[r][kk] = o0;
        }
        // stage W^T tile 128x32 (already bf16)
        {
            int c = t >> 1, kk = (t & 1) * 16;
            const int4* src = (const int4*)(W + (size_t)c * F_ + k0 + kk);
            *(int4*)&w_lds[c][kk]     = src[0];
            *(int4*)&w_lds[c][kk + 8] = src[1];
        }
        __syncthreads();

        short8 af = *(const short8*)&a_lds[wv_ * 16 + l15][l4 * 8];
        short8 bf[8];
#pragma unroll
        for (int ct = 0; ct < 8; ++ct)
            bf[ct] = *(const short8*)&w_lds[ct * 16 + l15][l4 * 8];

        if (mode < 2) {
#pragma unroll
            for (int ct = 0; ct < 8; ++ct)
                acc[ct] = __builtin_amdgcn_mfma_f32_16x16x32_bf16(af, bf[ct], acc[ct], 0, 0, 0);
        } else {
#pragma unroll
            for (int ct = 0; ct < 8; ++ct)
                acc[ct] = __builtin_amdgcn_mfma_f32_16x16x32_bf16(bf[ct], af, acc[ct], 0, 0, 0);
        }
        __syncthreads();
    }

    if (mode < 2) {
        u16* OUT = (mode == 0) ? qp : kp;
#pragma unroll
        for (int ct = 0; ct < 8; ++ct)
#pragma unroll
            for (int r = 0; r < 4; ++r) {
                int row = row0 + wv_ * 16 + l4 * 4 + r;
                int col = ct * 16 + l15;
                OUT[(size_t)row * DK_ + col] = f2bf(acc[ct][r]);
            }
    } else {
        // swapped operands: D[row=n][col=m] -> store transposed vpT[n][m]
#pragma unroll
        for (int ct = 0; ct < 8; ++ct)
#pragma unroll
            for (int r = 0; r < 4; ++r) {
                int n = ct * 16 + l4 * 4 + r;
                int m = row0 + wv_ * 16 + l15;
                vpT[(size_t)n * M_ + m] = f2bf(acc[ct][r]);
            }
    }
}

// ---------------------------------------------------------------------------
// Kernel 3: flash attention, in-block KV-split x4, direct-L2 K/V loads.
// Grid 512: b = blk&7 (XCD-pins batch KV in one L2), qi = blk>>3 -> 32 q rows.
// Block 256 thr = 4 waves; wave w handles KV slice [w*512, w*512+512) over
// the SAME 32 q rows; zero barriers in the main loop (P in wave-private LDS).
// End: m/l exchange + 2-slot rescale-combine in LDS.
// ---------------------------------------------------------------------------
__global__ __launch_bounds__(256, 2) void attn(const u16* __restrict__ qp,
                                               const u16* __restrict__ kp,
                                               const u16* __restrict__ vpT,
                                               float* __restrict__ out) {
    __shared__ float oA[32][132];                      // +4 pad: bank-spread
    __shared__ float oB[32][132];
    __shared__ __align__(16) unsigned char p_lds[4][4096];  // per-wave P slot
    __shared__ float m_lds[4][32], l_lds[4][32], gm_lds[32], gl_lds[32];

    const int t    = threadIdx.x;
    const int lane = t & 63;
    const int wv_  = t >> 6;
    const int l15  = lane & 15, l4 = lane >> 4;

    const int b  = blockIdx.x & 7;
    const int qi = blockIdx.x >> 3;
    const int qbase = b * S_ + qi * 32;

    // Q fragments (32 rows, scale folded into w_q; same for all 4 waves)
    short8 qf[2][4];
#pragma unroll
    for (int rt = 0; rt < 2; ++rt)
#pragma unroll
        for (int kc = 0; kc < 4; ++kc)
            qf[rt][kc] = *(const short8*)(qp + (size_t)(qbase + rt * 16 + l15) * DK_
                                             + kc * 32 + l4 * 8);

    f32x4 o[2][8];
#pragma unroll
    for (int i = 0; i < 2; ++i)
#pragma unroll
        for (int j = 0; j < 8; ++j) o[i][j] = f32x4{0.f, 0.f, 0.f, 0.f};
    float mrun[2][4], lrun[2][4];
#pragma unroll
    for (int i = 0; i < 2; ++i)
#pragma unroll
        for (int r = 0; r < 4; ++r) { mrun[i][r] = -3.0e38f; lrun[i][r] = 0.f; }

    unsigned char* pb = &p_lds[wv_][0];
    const int kv_lo = b * S_ + wv_ * 512;     // absolute row base of this wave's slice

    for (int kt = 0; kt < 8; ++kt) {
        const int kv0 = kv_lo + kt * 64;

        // ---- QK^T: s[q 32][kv 64], K fragments direct from L2
        f32x4 s[2][4];
#pragma unroll
        for (int i = 0; i < 2; ++i)
#pragma unroll
            for (int j = 0; j < 4; ++j) s[i][j] = f32x4{0.f, 0.f, 0.f, 0.f};
#pragma unroll
        for (int ct = 0; ct < 4; ++ct)
#pragma unroll
            for (int kc = 0; kc < 4; ++kc) {
                short8 kf = *(const short8*)(kp + (size_t)(kv0 + ct * 16 + l15) * DK_
                                                + kc * 32 + l4 * 8);
#pragma unroll
                for (int rt = 0; rt < 2; ++rt)
                    s[rt][ct] = __builtin_amdgcn_mfma_f32_16x16x32_bf16(
                        qf[rt][kc], kf, s[rt][ct], 0, 0, 0);
            }

        // ---- online softmax (+ P -> wave-private LDS as bf16)
#pragma unroll
        for (int rt = 0; rt < 2; ++rt) {
            float fs[4], sum[4];
#pragma unroll
            for (int r = 0; r < 4; ++r) {
                float v0 = fmaxf(fmaxf(s[rt][0][r], s[rt][1][r]),
                                 fmaxf(s[rt][2][r], s[rt][3][r]));
#pragma unroll
                for (int msk = 1; msk < 16; msk <<= 1)
                    v0 = fmaxf(v0, __shfl_xor(v0, msk, 64));
                float mn = fmaxf(mrun[rt][r], v0);
                fs[r] = exp2f((mrun[rt][r] - mn) * LOG2E);
                mrun[rt][r] = mn;
                sum[r] = 0.f;
            }
#pragma unroll
            for (int ct = 0; ct < 4; ++ct)
#pragma unroll
                for (int r = 0; r < 4; ++r) {
                    float p = exp2f((s[rt][ct][r] - mrun[rt][r]) * LOG2E);
                    sum[r] += p;
                    int prow = rt * 16 + l4 * 4 + r;
                    int pbyte = (prow * 128 + (ct * 16 + l15) * 2) ^ ((prow & 7) << 4);
                    *(u16*)(pb + pbyte) = f2bf(p);
                }
#pragma unroll
            for (int r = 0; r < 4; ++r) {
#pragma unroll
                for (int msk = 1; msk < 16; msk <<= 1)
                    sum[r] += __shfl_xor(sum[r], msk, 64);
                lrun[rt][r] = lrun[rt][r] * fs[r] + sum[r];
            }
#pragma unroll
            for (int ct = 0; ct < 8; ++ct)
#pragma unroll
                for (int r = 0; r < 4; ++r) o[rt][ct][r] *= fs[r];
        }

        // ---- PV: o[q 32][d 128] += P[q][kv] * V[kv][d], V direct from L2
#pragma unroll
        for (int kc = 0; kc < 2; ++kc) {
            short8 pf[2];
#pragma unroll
            for (int rt = 0; rt < 2; ++rt) {
                int prow = rt * 16 + l15;
                pf[rt] = *(const short8*)(pb + ((prow * 128 + kc * 64 + l4 * 16)
                                                ^ ((prow & 7) << 4)));
            }
#pragma unroll
            for (int ct = 0; ct < 8; ++ct) {
                short8 vf = *(const short8*)(vpT + (size_t)(ct * 16 + l15) * M_
                                                 + kv0 + kc * 32 + l4 * 8);
#pragma unroll
                for (int rt = 0; rt < 2; ++rt)
                    o[rt][ct] = __builtin_amdgcn_mfma_f32_16x16x32_bf16(
                        pf[rt], vf, o[rt][ct], 0, 0, 0);
            }
        }
    }

    // ---- cross-wave combine ----
    if (l15 == 0) {
#pragma unroll
        for (int rt = 0; rt < 2; ++rt)
#pragma unroll
            for (int r = 0; r < 4; ++r) {
                m_lds[wv_][rt * 16 + l4 * 4 + r] = mrun[rt][r];
                l_lds[wv_][rt * 16 + l4 * 4 + r] = lrun[rt][r];
            }
    }
    __syncthreads();
    if (t < 32) {
        float gm = -3.0e38f;
#pragma unroll
        for (int w = 0; w < 4; ++w) gm = fmaxf(gm, m_lds[w][t]);
        float gl = 0.f;
#pragma unroll
        for (int w = 0; w < 4; ++w)
            gl += l_lds[w][t] * exp2f((m_lds[w][t] - gm) * LOG2E);
        gm_lds[t] = gm;
        gl_lds[t] = gl;
    }
    __syncthreads();

    float* slot = (wv_ & 1) ? &oB[0][0] : &oA[0][0];
    float sc[2][4];
#pragma unroll
    for (int rt = 0; rt < 2; ++rt)
#pragma unroll
        for (int r = 0; r < 4; ++r) {
            int row = rt * 16 + l4 * 4 + r;
            sc[rt][r] = exp2f((mrun[rt][r] - gm_lds[row]) * LOG2E);
        }
    if (wv_ < 2) {
#pragma unroll
        for (int rt = 0; rt < 2; ++rt)
#pragma unroll
            for (int ct = 0; ct < 8; ++ct)
#pragma unroll
                for (int r = 0; r < 4; ++r) {
                    int row = rt * 16 + l4 * 4 + r;
                    slot[row * 132 + ct * 16 + l15] = o[rt][ct][r] * sc[rt][r];
                }
    }
    __syncthreads();
    if (wv_ >= 2) {
#pragma unroll
        for (int rt = 0; rt < 2; ++rt)
#pragma unroll
            for (int ct = 0; ct < 8; ++ct)
#pragma unroll
                for (int r = 0; r < 4; ++r) {
                    int row = rt * 16 + l4 * 4 + r;
                    slot[row * 132 + ct * 16 + l15] += o[rt][ct][r] * sc[rt][r];
                }
    }
    __syncthreads();

    // ---- final: (oA+oB)/gl -> out (fp32), thread t: row t>>3, cols (t&7)*16..+16
    {
        int row = t >> 3, c0 = (t & 7) * 16;
        float inv = 1.0f / gl_lds[row];
        float* dst = out + (size_t)(qbase + row) * DK_ + c0;
#pragma unroll
        for (int j = 0; j < 16; j += 4) {
            float4 v;
            v.x = (oA[row][c0 + j]     + oB[row][c0 + j])     * inv;
            v.y = (oA[row][c0 + j + 1] + oB[row][c0 + j + 1]) * inv;
            v.z = (oA[row][c0 + j + 2] + oB[row][c0 + j + 2]) * inv;
            v.w = (oA[row][c0 + j + 3] + oB[row][c0 + j + 3]) * inv;
            *(float4*)(dst + j) = v;
        }
    }
}

// ---------------------------------------------------------------------------
extern "C" void kernel_launch(void* const* d_in, const int* in_sizes, int n_in,
                              void* d_out, int out_size, void* d_ws, size_t ws_size,
                              hipStream_t stream) {
    const float* q  = (const float*)d_in[0];
    const float* k  = (const float*)d_in[1];
    const float* v  = (const float*)d_in[2];
    const float* wq = (const float*)d_in[3];
    const float* wk = (const float*)d_in[4];
    const float* wv = (const float*)d_in[5];
    float* out = (float*)d_out;

    char* ws = (char*)d_ws;
    u16* WT  = (u16*)ws;                                   // 3*128*1024*2 = 786432 B
    u16* qp  = (u16*)(ws + 786432);                        // 4 MB
    u16* kp  = (u16*)(ws + 786432 + 4194304);              // 4 MB
    u16* vpT = (u16*)(ws + 786432 + 2 * 4194304);          // 4 MB  (total ~12.75 MB)

    prep_wt<<<dim3(1536), dim3(256), 0, stream>>>(wq, wk, wv, WT);
    proj<<<dim3(256, 3), dim3(256), 0, stream>>>(q, k, v, WT, qp, kp, vpT);
    attn<<<dim3(512), dim3(256), 0, stream>>>(qp, kp, vpT, out);
}